// Round 3
// baseline (117.981 us; speedup 1.0000x reference)
//
#include <hip/hip_runtime.h>

// Problem constants (fixed by setup_inputs): x(64,32768,6) f32, templates(16,6,80), delays(16,6)
#define BB 64
#define SS 32768
#define FF 6
#define EE 16
#define LL 80
#define KK 480      // F*L
#define NSL 15      // K / 32
#define TBLK 256    // time positions per block
#define NPHI 4      // phase copies (t = t0 + phi + 4*row)
#define WROW 332    // xs row length in elems (exactly 332 needed; *2B = 664, 8B-aligned)
#define WUNITS 166  // position-pairs staged per copy (332 positions)

typedef _Float16 half8 __attribute__((ext_vector_type(8)));
typedef float f32x4 __attribute__((ext_vector_type(4)));

// Build reversed, delay-shifted kernel: wrev[e*480 + f*80 + r] = delayed[e,f,79-r]
__global__ void prep_kernel(const float* __restrict__ tpl, const float* __restrict__ dly,
                            _Float16* __restrict__ wrev) {
    int n = blockIdx.x * 256 + threadIdx.x;
    if (n >= EE * KK) return;
    int e = n / KK, k = n - e * KK;
    int f = k / LL, r = k - f * LL;
    int m = LL - 1 - r;
    float dl = fminf(fmaxf(dly[e * FF + f], -10.f), 10.f);
    int d = (int)rintf(dl);                 // RNE, matches jnp.round
    int src = m - d;
    float v = (src >= 0 && src < LL) ? tpl[(e * FF + f) * LL + src] : 0.f;
    wrev[n] = (_Float16)v;                  // NOT pre-scaled (avoid f16 denormals)
}

template <bool FROM_WS>
__global__ __launch_bounds__(256, 8) void corr_kernel(
    const float* __restrict__ x, const float* __restrict__ tpl,
    const float* __restrict__ dly, const _Float16* __restrict__ wrev,
    float* __restrict__ out) {
    __shared__ alignas(16) _Float16 xs[NPHI][FF][WROW];      // 15,936 B

    int tid = threadIdx.x;
    int b = blockIdx.x >> 7;              // 128 t-blocks per batch
    int t0 = (blockIdx.x & 127) << 8;     // *256

    int lane = tid & 63;
    int wid = tid >> 6;                   // 4 waves = 4 phases
    int e = lane & 15;
    int g = lane >> 4;

    // ---- B fragments straight from global (15 KB total -> L2/L3 resident) ----
    half8 bq[NSL];
    if constexpr (FROM_WS) {
        #pragma unroll
        for (int s = 0; s < NSL; s++)
            bq[s] = *(const half8*)&wrev[e * KK + 32 * s + 8 * g];   // 16B aligned
    } else {
        __shared__ _Float16 Wlds[EE * KK];
        for (int n = tid; n < EE * KK; n += 256) {
            int ee = n / KK, k = n - ee * KK;
            int f = k / LL, r = k - f * LL;
            int m = LL - 1 - r;
            float dl = fminf(fmaxf(dly[ee * FF + f], -10.f), 10.f);
            int d = (int)rintf(dl);
            int src = m - d;
            float v = (src >= 0 && src < LL) ? tpl[(ee * FF + f) * LL + src] : 0.f;
            Wlds[n] = (_Float16)v;
        }
        __syncthreads();
        #pragma unroll
        for (int s = 0; s < NSL; s++)
            bq[s] = *(const half8*)&Wlds[e * KK + 32 * s + 8 * g];
    }

    // ---- stage x: 4 phase copies, copy phi covers positions [t0+phi-39, t0+phi+293) ----
    const float* xb = x + (size_t)b * (SS * FF);
    for (int it = tid; it < NPHI * WUNITS; it += 256) {   // pairs of positions
        int phi = it / WUNITS;
        int i = (it - phi * WUNITS) * 2;
        int pos = t0 + phi - 39 + i;
        float va[12];
        if (pos >= 0 && pos <= SS - 2) {
            const float* xp = xb + (size_t)pos * FF;   // 12 contiguous floats, 8B-aligned
            #pragma unroll
            for (int q = 0; q < 6; q++)
                *(float2*)&va[2 * q] = *(const float2*)&xp[2 * q];
        } else {
            #pragma unroll
            for (int q = 0; q < 2; q++) {
                int p = pos + q;
                bool ok = (p >= 0) && (p < SS);
                #pragma unroll
                for (int f = 0; f < FF; f++)
                    va[q * 6 + f] = ok ? xb[(size_t)p * FF + f] : 0.f;
            }
        }
        #pragma unroll
        for (int f = 0; f < FF; f++) {
#if __has_builtin(__builtin_amdgcn_cvt_pkrtz)
            __fp16 __attribute__((ext_vector_type(2))) hp =
                __builtin_amdgcn_cvt_pkrtz(va[f], va[6 + f]);
            *(decltype(hp)*)&xs[phi][f][i] = hp;      // i even -> 4B aligned
#else
            xs[phi][f][i] = (_Float16)va[f];
            xs[phi][f][i + 1] = (_Float16)va[6 + f];
#endif
        }
    }
    __syncthreads();

    int phi = wid;
    const char* xph = (const char*)&xs[phi][0][0];
    f32x4 acc[4];
    #pragma unroll
    for (int tt = 0; tt < 4; tt++) acc[tt] = (f32x4){0.f, 0.f, 0.f, 0.f};

    #pragma unroll
    for (int tt = 0; tt < 4; tt++) {
        int R = tt * 16 + (lane & 15);    // A-row position index (t-stride 4)
        #pragma unroll
        for (int s = 0; s < NSL; s++) {
            int k0 = 32 * s + 8 * g;
            int f = (k0 * 205) >> 14;        // exact k0/80 for k0 in [0,480)
            int r0 = k0 - 80 * f;
            const char* p = xph + 2 * (f * WROW + 4 * R + r0);   // 8B-aligned
            uint2 lo = *(const uint2*)p;
            uint2 hi = *(const uint2*)(p + 8);
            union { unsigned u[4]; half8 h; } av;
            av.u[0] = lo.x; av.u[1] = lo.y; av.u[2] = hi.x; av.u[3] = hi.y;
            acc[tt] = __builtin_amdgcn_mfma_f32_16x16x32_f16(av.h, bq[s], acc[tt], 0, 0, 0);
        }
    }

    // D layout: row = g*4 + j (within 16-row tile), col = e ; t = t0 + phi + 4*(tt*16 + row)
    #pragma unroll
    for (int tt = 0; tt < 4; tt++) {
        #pragma unroll
        for (int j = 0; j < 4; j++) {
            int row = tt * 16 + g * 4 + j;
            int t = t0 + phi + 4 * row;
            float v = acc[tt][j] * (1.0f / 480.0f);
            if (t == SS - 1) v = 0.f;        // reference zero-pads the last position
            out[((size_t)b * SS + t) * EE + e] = v;
        }
    }
}

extern "C" void kernel_launch(void* const* d_in, const int* in_sizes, int n_in,
                              void* d_out, int out_size, void* d_ws, size_t ws_size,
                              hipStream_t stream) {
    const float* x = (const float*)d_in[0];
    const float* tpl = (const float*)d_in[1];
    const float* dly = (const float*)d_in[2];
    float* out = (float*)d_out;

    int grid = BB * (SS / TBLK);   // 8192 blocks, 256 threads (4 waves)
    if (ws_size >= (size_t)(EE * KK * sizeof(_Float16))) {
        _Float16* wrev = (_Float16*)d_ws;
        prep_kernel<<<(EE * KK + 255) / 256, 256, 0, stream>>>(tpl, dly, wrev);
        corr_kernel<true><<<grid, 256, 0, stream>>>(x, tpl, dly, wrev, out);
    } else {
        corr_kernel<false><<<grid, 256, 0, stream>>>(x, tpl, dly, nullptr, out);
    }
}

// Round 4
// 73.941 us; speedup vs baseline: 1.5956x; 1.5956x over previous
//
#include <hip/hip_runtime.h>

// Problem constants (fixed by setup_inputs): x(64,32768,6) f32, templates(16,6,80), delays(16,6)
#define BB 64
#define SS 32768
#define FF 6
#define EE 16
#define LL 80
#define KK 480      // F*L
#define NSL 15      // K / 32
#define TBLK 256    // time positions per block
#define NPHI 4      // phase copies (t = t0 + phi + 4*row)
#define WROW 332    // xs row length in elems (exactly 332 needed; *2B = 664, 8B-aligned)
#define WUNITS 166  // position-pairs staged per copy (332 positions)

typedef _Float16 half8 __attribute__((ext_vector_type(8)));
typedef float f32x4 __attribute__((ext_vector_type(4)));

// Build reversed, delay-shifted kernel: wrev[e*480 + f*80 + r] = delayed[e,f,79-r]
__global__ void prep_kernel(const float* __restrict__ tpl, const float* __restrict__ dly,
                            _Float16* __restrict__ wrev) {
    int n = blockIdx.x * 256 + threadIdx.x;
    if (n >= EE * KK) return;
    int e = n / KK, k = n - e * KK;
    int f = k / LL, r = k - f * LL;
    int m = LL - 1 - r;
    float dl = fminf(fmaxf(dly[e * FF + f], -10.f), 10.f);
    int d = (int)rintf(dl);                 // RNE, matches jnp.round
    int src = m - d;
    float v = (src >= 0 && src < LL) ? tpl[(e * FF + f) * LL + src] : 0.f;
    wrev[n] = (_Float16)v;                  // NOT pre-scaled (avoid f16 denormals)
}

template <bool FROM_WS>
__global__ __launch_bounds__(256, 4) void corr_kernel(   // 4 waves/EU -> 128-VGPR budget (NO spill)
    const float* __restrict__ x, const float* __restrict__ tpl,
    const float* __restrict__ dly, const _Float16* __restrict__ wrev,
    float* __restrict__ out) {
    __shared__ alignas(16) _Float16 xs[NPHI][FF][WROW];      // 15,936 B

    int tid = threadIdx.x;
    int b = blockIdx.x >> 7;              // 128 t-blocks per batch
    int t0 = (blockIdx.x & 127) << 8;     // *256

    int lane = tid & 63;
    int wid = tid >> 6;                   // 4 waves = 4 phases
    int e = lane & 15;
    int g = lane >> 4;

    // ---- B fragments straight from global (15 KB total -> L2/L3 resident), held in 60 VGPRs ----
    half8 bq[NSL];
    if constexpr (FROM_WS) {
        #pragma unroll
        for (int s = 0; s < NSL; s++)
            bq[s] = *(const half8*)&wrev[e * KK + 32 * s + 8 * g];   // 16B aligned
    } else {
        __shared__ _Float16 Wlds[EE * KK];
        for (int n = tid; n < EE * KK; n += 256) {
            int ee = n / KK, k = n - ee * KK;
            int f = k / LL, r = k - f * LL;
            int m = LL - 1 - r;
            float dl = fminf(fmaxf(dly[ee * FF + f], -10.f), 10.f);
            int d = (int)rintf(dl);
            int src = m - d;
            float v = (src >= 0 && src < LL) ? tpl[(ee * FF + f) * LL + src] : 0.f;
            Wlds[n] = (_Float16)v;
        }
        __syncthreads();
        #pragma unroll
        for (int s = 0; s < NSL; s++)
            bq[s] = *(const half8*)&Wlds[e * KK + 32 * s + 8 * g];
    }

    // ---- stage x: 4 phase copies, copy phi covers positions [t0+phi-39, t0+phi+293) ----
    const float* xb = x + (size_t)b * (SS * FF);
    for (int it = tid; it < NPHI * WUNITS; it += 256) {   // pairs of positions
        int phi = it / WUNITS;
        int i = (it - phi * WUNITS) * 2;
        int pos = t0 + phi - 39 + i;
        float va[12];
        if (pos >= 0 && pos <= SS - 2) {
            const float* xp = xb + (size_t)pos * FF;   // 12 contiguous floats, 8B-aligned
            #pragma unroll
            for (int q = 0; q < 6; q++)
                *(float2*)&va[2 * q] = *(const float2*)&xp[2 * q];
        } else {
            #pragma unroll
            for (int q = 0; q < 2; q++) {
                int p = pos + q;
                bool ok = (p >= 0) && (p < SS);
                #pragma unroll
                for (int f = 0; f < FF; f++)
                    va[q * 6 + f] = ok ? xb[(size_t)p * FF + f] : 0.f;
            }
        }
        #pragma unroll
        for (int f = 0; f < FF; f++) {
#if __has_builtin(__builtin_amdgcn_cvt_pkrtz)
            __fp16 __attribute__((ext_vector_type(2))) hp =
                __builtin_amdgcn_cvt_pkrtz(va[f], va[6 + f]);
            *(decltype(hp)*)&xs[phi][f][i] = hp;      // i even -> 4B aligned
#else
            xs[phi][f][i] = (_Float16)va[f];
            xs[phi][f][i + 1] = (_Float16)va[6 + f];
#endif
        }
    }
    __syncthreads();

    int phi = wid;
    const char* xph = (const char*)&xs[phi][0][0];
    f32x4 acc[4];
    #pragma unroll
    for (int tt = 0; tt < 4; tt++) acc[tt] = (f32x4){0.f, 0.f, 0.f, 0.f};

    #pragma unroll
    for (int tt = 0; tt < 4; tt++) {
        int R = tt * 16 + (lane & 15);    // A-row position index (t-stride 4)
        #pragma unroll
        for (int s = 0; s < NSL; s++) {
            int k0 = 32 * s + 8 * g;
            int f = (k0 * 205) >> 14;        // exact k0/80 for k0 in [0,480)
            int r0 = k0 - 80 * f;
            const char* p = xph + 2 * (f * WROW + 4 * R + r0);   // 8B-aligned
            uint2 lo = *(const uint2*)p;
            uint2 hi = *(const uint2*)(p + 8);
            union { unsigned u[4]; half8 h; } av;
            av.u[0] = lo.x; av.u[1] = lo.y; av.u[2] = hi.x; av.u[3] = hi.y;
            acc[tt] = __builtin_amdgcn_mfma_f32_16x16x32_f16(av.h, bq[s], acc[tt], 0, 0, 0);
        }
    }

    // D layout: row = g*4 + j (within 16-row tile), col = e ; t = t0 + phi + 4*(tt*16 + row)
    #pragma unroll
    for (int tt = 0; tt < 4; tt++) {
        #pragma unroll
        for (int j = 0; j < 4; j++) {
            int row = tt * 16 + g * 4 + j;
            int t = t0 + phi + 4 * row;
            float v = acc[tt][j] * (1.0f / 480.0f);
            if (t == SS - 1) v = 0.f;        // reference zero-pads the last position
            out[((size_t)b * SS + t) * EE + e] = v;
        }
    }
}

extern "C" void kernel_launch(void* const* d_in, const int* in_sizes, int n_in,
                              void* d_out, int out_size, void* d_ws, size_t ws_size,
                              hipStream_t stream) {
    const float* x = (const float*)d_in[0];
    const float* tpl = (const float*)d_in[1];
    const float* dly = (const float*)d_in[2];
    float* out = (float*)d_out;

    int grid = BB * (SS / TBLK);   // 8192 blocks, 256 threads (4 waves)
    if (ws_size >= (size_t)(EE * KK * sizeof(_Float16))) {
        _Float16* wrev = (_Float16*)d_ws;
        prep_kernel<<<(EE * KK + 255) / 256, 256, 0, stream>>>(tpl, dly, wrev);
        corr_kernel<true><<<grid, 256, 0, stream>>>(x, tpl, dly, wrev, out);
    } else {
        corr_kernel<false><<<grid, 256, 0, stream>>>(x, tpl, dly, nullptr, out);
    }
}

// Round 5
// 68.261 us; speedup vs baseline: 1.7284x; 1.0832x over previous
//
#include <hip/hip_runtime.h>

// Problem constants (fixed by setup_inputs): x(64,32768,6) f32, templates(16,6,80), delays(16,6)
#define BB 64
#define SS 32768
#define FF 6
#define EE 16
#define LL 80
#define KK 480      // F*L
#define NSL 15      // K / 32
#define TBLK 256    // time positions per block
#define NPHI 4      // phase copies (t = t0 + phi + 4*row)
#define WROW 332    // xs row length in elems (exactly 332 needed; *2B = 664, 8B-aligned)
#define WUNITS 166  // position-pairs staged per copy (332 positions)

typedef _Float16 half8 __attribute__((ext_vector_type(8)));
typedef float f32x4 __attribute__((ext_vector_type(4)));

// Build reversed, delay-shifted kernel: wrev[e*480 + f*80 + r] = delayed[e,f,79-r]
__global__ void prep_kernel(const float* __restrict__ tpl, const float* __restrict__ dly,
                            _Float16* __restrict__ wrev) {
    int n = blockIdx.x * 256 + threadIdx.x;
    if (n >= EE * KK) return;
    int e = n / KK, k = n - e * KK;
    int f = k / LL, r = k - f * LL;
    int m = LL - 1 - r;
    float dl = fminf(fmaxf(dly[e * FF + f], -10.f), 10.f);
    int d = (int)rintf(dl);                 // RNE, matches jnp.round
    int src = m - d;
    float v = (src >= 0 && src < LL) ? tpl[(e * FF + f) * LL + src] : 0.f;
    wrev[n] = (_Float16)v;                  // NOT pre-scaled (avoid f16 denormals)
}

template <bool FROM_WS>
__global__ __launch_bounds__(256, 4) void corr_kernel(   // 4 waves/EU -> 128-VGPR budget
    const float* __restrict__ x, const float* __restrict__ tpl,
    const float* __restrict__ dly, const _Float16* __restrict__ wrev,
    float* __restrict__ out) {
    __shared__ alignas(16) _Float16 xs[NPHI][FF][WROW];      // 15,936 B

    int tid = threadIdx.x;
    int b = blockIdx.x >> 7;              // 128 t-blocks per batch
    int t0 = (blockIdx.x & 127) << 8;     // *256

    int lane = tid & 63;
    int wid = tid >> 6;                   // 4 waves = 4 phases
    int e = lane & 15;
    int g = lane >> 4;

    // ---- stage x: 4 phase copies, copy phi covers positions [t0+phi-39, t0+phi+293) ----
    const float* xb = x + (size_t)b * (SS * FF);
    for (int it = tid; it < NPHI * WUNITS; it += 256) {   // pairs of positions
        int phi = it / WUNITS;
        int i = (it - phi * WUNITS) * 2;
        int pos = t0 + phi - 39 + i;
        float va[12];
        if (pos >= 0 && pos <= SS - 2) {
            const float* xp = xb + (size_t)pos * FF;   // 12 contiguous floats, 8B-aligned
            #pragma unroll
            for (int q = 0; q < 6; q++)
                *(float2*)&va[2 * q] = *(const float2*)&xp[2 * q];
        } else {
            #pragma unroll
            for (int q = 0; q < 2; q++) {
                int p = pos + q;
                bool ok = (p >= 0) && (p < SS);
                #pragma unroll
                for (int f = 0; f < FF; f++)
                    va[q * 6 + f] = ok ? xb[(size_t)p * FF + f] : 0.f;
            }
        }
        #pragma unroll
        for (int f = 0; f < FF; f++) {
#if __has_builtin(__builtin_amdgcn_cvt_pkrtz)
            __fp16 __attribute__((ext_vector_type(2))) hp =
                __builtin_amdgcn_cvt_pkrtz(va[f], va[6 + f]);
            *(decltype(hp)*)&xs[phi][f][i] = hp;      // i even -> 4B aligned
#else
            xs[phi][f][i] = (_Float16)va[f];
            xs[phi][f][i + 1] = (_Float16)va[6 + f];
#endif
        }
    }

    // ---- B fragments into VGPRs (15 x f32x4 = 60 VGPRs), PINNED so the compiler
    //      cannot sink/rematerialize the loads inside the MFMA loop ----
    f32x4 bqv[NSL];
    if constexpr (FROM_WS) {
        #pragma unroll
        for (int s = 0; s < NSL; s++)
            bqv[s] = *(const f32x4*)&wrev[e * KK + 32 * s + 8 * g];   // 16B aligned, L2/L3-hit
    } else {
        __shared__ _Float16 Wlds[EE * KK];
        for (int n = tid; n < EE * KK; n += 256) {
            int ee = n / KK, k = n - ee * KK;
            int f = k / LL, r = k - f * LL;
            int m = LL - 1 - r;
            float dl = fminf(fmaxf(dly[ee * FF + f], -10.f), 10.f);
            int d = (int)rintf(dl);
            int src = m - d;
            float v = (src >= 0 && src < LL) ? tpl[(ee * FF + f) * LL + src] : 0.f;
            Wlds[n] = (_Float16)v;
        }
        __syncthreads();
        #pragma unroll
        for (int s = 0; s < NSL; s++)
            bqv[s] = *(const f32x4*)&Wlds[e * KK + 32 * s + 8 * g];
    }
    #pragma unroll
    for (int s = 0; s < NSL; s++)
        asm volatile("" : "+v"(bqv[s]));   // pin: B stays in registers across the loop

    __syncthreads();

    int phi = wid;
    const char* xph = (const char*)&xs[phi][0][0];
    f32x4 acc[4];
    #pragma unroll
    for (int tt = 0; tt < 4; tt++) acc[tt] = (f32x4){0.f, 0.f, 0.f, 0.f};

    #pragma unroll
    for (int tt = 0; tt < 4; tt++) {
        int R = tt * 16 + (lane & 15);    // A-row position index (t-stride 4)
        #pragma unroll
        for (int s = 0; s < NSL; s++) {
            int k0 = 32 * s + 8 * g;
            int f = (k0 * 205) >> 14;        // exact k0/80 for k0 in [0,480)
            int r0 = k0 - 80 * f;
            const char* p = xph + 2 * (f * WROW + 4 * R + r0);   // 8B-aligned
            uint2 lo = *(const uint2*)p;
            uint2 hi = *(const uint2*)(p + 8);
            union { unsigned u[4]; half8 h; } av;
            av.u[0] = lo.x; av.u[1] = lo.y; av.u[2] = hi.x; av.u[3] = hi.y;
            union { f32x4 f4; half8 h; } bv;
            bv.f4 = bqv[s];
            acc[tt] = __builtin_amdgcn_mfma_f32_16x16x32_f16(av.h, bv.h, acc[tt], 0, 0, 0);
        }
    }

    // D layout: row = g*4 + j (within 16-row tile), col = e ; t = t0 + phi + 4*(tt*16 + row)
    #pragma unroll
    for (int tt = 0; tt < 4; tt++) {
        #pragma unroll
        for (int j = 0; j < 4; j++) {
            int row = tt * 16 + g * 4 + j;
            int t = t0 + phi + 4 * row;
            float v = acc[tt][j] * (1.0f / 480.0f);
            if (t == SS - 1) v = 0.f;        // reference zero-pads the last position
            out[((size_t)b * SS + t) * EE + e] = v;
        }
    }
}

extern "C" void kernel_launch(void* const* d_in, const int* in_sizes, int n_in,
                              void* d_out, int out_size, void* d_ws, size_t ws_size,
                              hipStream_t stream) {
    const float* x = (const float*)d_in[0];
    const float* tpl = (const float*)d_in[1];
    const float* dly = (const float*)d_in[2];
    float* out = (float*)d_out;

    int grid = BB * (SS / TBLK);   // 8192 blocks, 256 threads (4 waves)
    if (ws_size >= (size_t)(EE * KK * sizeof(_Float16))) {
        _Float16* wrev = (_Float16*)d_ws;
        prep_kernel<<<(EE * KK + 255) / 256, 256, 0, stream>>>(tpl, dly, wrev);
        corr_kernel<true><<<grid, 256, 0, stream>>>(x, tpl, dly, wrev, out);
    } else {
        corr_kernel<false><<<grid, 256, 0, stream>>>(x, tpl, dly, nullptr, out);
    }
}